// Round 1
// baseline (234.230 us; speedup 1.0000x reference)
//
#include <hip/hip_runtime.h>
#include <stdint.h>

typedef __attribute__((ext_vector_type(8))) short short8;
typedef __attribute__((ext_vector_type(4))) float floatx4;

__device__ inline unsigned short f2bf(float x) {
  union { float f; unsigned int u; } v; v.f = x;
  unsigned int r = v.u + 0x7FFFu + ((v.u >> 16) & 1u);  // RNE
  return (unsigned short)(r >> 16);
}

// ---------------------------------------------------------------------------
// pack_a: A_bf16[4096][2048] = bf16([x | h]) ; 8 elems/thread, 16B stores
// ---------------------------------------------------------------------------
__global__ void pack_a(const float* __restrict__ x, const float* __restrict__ h,
                       unsigned short* __restrict__ A) {
  int idx = blockIdx.x * 256 + threadIdx.x;  // 1,048,576 threads
  int row = idx >> 8;                        // 0..4095
  int kc  = (idx & 255) << 3;                // 0..2040, step 8
  const float* src = (kc < 1024) ? (x + (size_t)row * 1024 + kc)
                                 : (h + (size_t)row * 1024 + (kc - 1024));
  float4 a = ((const float4*)src)[0];
  float4 b = ((const float4*)src)[1];
  uint4 o;
  o.x = f2bf(a.x) | ((unsigned)f2bf(a.y) << 16);
  o.y = f2bf(a.z) | ((unsigned)f2bf(a.w) << 16);
  o.z = f2bf(b.x) | ((unsigned)f2bf(b.y) << 16);
  o.w = f2bf(b.z) | ((unsigned)f2bf(b.w) << 16);
  *(uint4*)(A + (size_t)row * 2048 + kc) = o;
}

// ---------------------------------------------------------------------------
// pack_w: Wt_bf16[4096 n][2048 k] = bf16(transpose([w_i ; w_h]))
// 64x64 f32 tiles through LDS (padded +1 to keep banks clean)
// grid: 2048 blocks = 64 n-tiles x 32 k-tiles, 256 threads
// ---------------------------------------------------------------------------
__global__ void pack_w(const float* __restrict__ wi, const float* __restrict__ wh,
                       unsigned short* __restrict__ Wt) {
  __shared__ float tile[64][65];
  int kt = blockIdx.x & 31;
  int nt = blockIdx.x >> 5;
  int k0 = kt << 6, n0 = nt << 6;
  const float* src = (k0 < 1024) ? (wi + (size_t)k0 * 4096)
                                 : (wh + (size_t)(k0 - 1024) * 4096);
  int t = threadIdx.x;
  int c4 = (t & 15) << 2, rr = t >> 4;
#pragma unroll
  for (int p = 0; p < 4; ++p) {
    int kk = rr + p * 16;
    float4 v = *(const float4*)(src + (size_t)kk * 4096 + n0 + c4);
    tile[kk][c4 + 0] = v.x; tile[kk][c4 + 1] = v.y;
    tile[kk][c4 + 2] = v.z; tile[kk][c4 + 3] = v.w;
  }
  __syncthreads();
  int k8 = (t & 7) << 3, nn = t >> 3;
#pragma unroll
  for (int p = 0; p < 2; ++p) {
    int n = nn + p * 32;
    uint4 o;
    o.x = f2bf(tile[k8 + 0][n]) | ((unsigned)f2bf(tile[k8 + 1][n]) << 16);
    o.y = f2bf(tile[k8 + 2][n]) | ((unsigned)f2bf(tile[k8 + 3][n]) << 16);
    o.z = f2bf(tile[k8 + 4][n]) | ((unsigned)f2bf(tile[k8 + 5][n]) << 16);
    o.w = f2bf(tile[k8 + 6][n]) | ((unsigned)f2bf(tile[k8 + 7][n]) << 16);
    *(uint4*)(Wt + (size_t)(n0 + n) * 2048 + k0 + k8) = o;
  }
}

// ---------------------------------------------------------------------------
// gemm_bt: C[4096][4096] f32 = A[4096][2048]bf16 . Bt[4096][2048]bf16^T
// m97 structure: 128x128 tile, BK=32, 4 waves (2x2), 4x4 frags of 16x16x32,
// global_load_lds width=16 staging, 2-barrier K-loop.
// ---------------------------------------------------------------------------
__device__ inline void gl_lds16(const void* g, void* l) {
  __builtin_amdgcn_global_load_lds(
      (const __attribute__((address_space(1))) void*)g,
      (__attribute__((address_space(3))) void*)l, 16, 0, 0);
}

__global__ void gemm_bt(const unsigned short* __restrict__ A,
                        const unsigned short* __restrict__ Bt,
                        float* __restrict__ C) {
  constexpr int K = 2048, N = 4096;
  __shared__ char AsB[128 * 64];  // 128 rows x 32 bf16 (64 B)
  __shared__ char BsB[128 * 64];
  const int tid  = threadIdx.x;
  const int lane = tid & 63;
  const int wave = tid >> 6;
  const int wm = wave >> 1, wn = wave & 1;
  const int m0 = blockIdx.y << 7, n0 = blockIdx.x << 7;

  // staging: thread covers 16B at flat offset tid*16 and +4096 in each tile
  const int r  = tid >> 2;          // row 0..63
  const int cb = (tid & 3) << 4;    // byte col in 64B row
  const char* aS0 = (const char*)A + (size_t)(m0 + r) * K * 2 + cb;
  const char* aS1 = aS0 + (size_t)64 * K * 2;
  const char* bS0 = (const char*)Bt + (size_t)(n0 + r) * K * 2 + cb;
  const char* bS1 = bS0 + (size_t)64 * K * 2;
  char* aD0 = AsB + tid * 16;
  char* aD1 = AsB + 4096 + tid * 16;
  char* bD0 = BsB + tid * 16;
  char* bD1 = BsB + 4096 + tid * 16;

  floatx4 acc[4][4] = {};
  const int rA = (wm << 6) + (lane & 15);   // LDS row for A frags (+f*16)
  const int rB = (wn << 6) + (lane & 15);   // LDS row for B frags (+f*16)
  const int kb = (lane >> 4) << 4;          // byte offset of k-quad (8 bf16)

  for (int ks = 0; ks < K; ks += 32) {
    gl_lds16(aS0, aD0); gl_lds16(aS1, aD1);
    gl_lds16(bS0, bD0); gl_lds16(bS1, bD1);
    aS0 += 64; aS1 += 64; bS0 += 64; bS1 += 64;
    __syncthreads();
    short8 af[4], bfr[4];
#pragma unroll
    for (int f = 0; f < 4; ++f) {
      af[f]  = *(const short8*)(AsB + (rA + f * 16) * 64 + kb);
      bfr[f] = *(const short8*)(BsB + (rB + f * 16) * 64 + kb);
    }
#pragma unroll
    for (int i = 0; i < 4; ++i)
#pragma unroll
      for (int j = 0; j < 4; ++j)
        acc[i][j] = __builtin_amdgcn_mfma_f32_16x16x32_bf16(af[i], bfr[j], acc[i][j], 0, 0, 0);
    __syncthreads();
  }

  // epilogue: C/D map col=lane&15, row=(lane>>4)*4+reg
  const int er = (lane >> 4) << 2;
  const int ec = lane & 15;
#pragma unroll
  for (int i = 0; i < 4; ++i) {
#pragma unroll
    for (int rg = 0; rg < 4; ++rg) {
      int row = m0 + (wm << 6) + i * 16 + er + rg;
      float* cp = C + (size_t)row * N + n0 + (wn << 6) + ec;
#pragma unroll
      for (int j = 0; j < 4; ++j) cp[j * 16] = acc[i][j][rg];
    }
  }
}

// ---------------------------------------------------------------------------
// lstm_ew: gates + cell update. out = [h_new (4M) | c_new (4M)] f32
// ---------------------------------------------------------------------------
__device__ inline float sigm(float x)  { return 1.0f / (1.0f + __expf(-x)); }
__device__ inline float tanhx(float x) { return 2.0f / (1.0f + __expf(-2.0f * x)) - 1.0f; }

__global__ void lstm_ew(const float* __restrict__ ifgo, const float* __restrict__ ct,
                        const float* __restrict__ bi, const float* __restrict__ bh,
                        float* __restrict__ out) {
  int idx = blockIdx.x * 256 + threadIdx.x;  // 1,048,576 threads
  int b  = idx >> 8;
  int hc = (idx & 255) << 2;
  const float* base = ifgo + (size_t)b * 4096;
  float4 zi = *(const float4*)(base + hc);
  float4 zf = *(const float4*)(base + 1024 + hc);
  float4 zg = *(const float4*)(base + 2048 + hc);
  float4 zo = *(const float4*)(base + 3072 + hc);
  float4 cv = *(const float4*)(ct + (size_t)b * 1024 + hc);
  float4 bi0 = *(const float4*)(bi + hc);
  float4 bi1 = *(const float4*)(bi + 1024 + hc);
  float4 bi2 = *(const float4*)(bi + 2048 + hc);
  float4 bi3 = *(const float4*)(bi + 3072 + hc);
  float4 bh0 = *(const float4*)(bh + hc);
  float4 bh1 = *(const float4*)(bh + 1024 + hc);
  float4 bh2 = *(const float4*)(bh + 2048 + hc);
  float4 bh3 = *(const float4*)(bh + 3072 + hc);

  const float* zia = (const float*)&zi; const float* zfa = (const float*)&zf;
  const float* zga = (const float*)&zg; const float* zoa = (const float*)&zo;
  const float* cva = (const float*)&cv;
  const float* b0a = (const float*)&bi0; const float* b1a = (const float*)&bi1;
  const float* b2a = (const float*)&bi2; const float* b3a = (const float*)&bi3;
  const float* h0a = (const float*)&bh0; const float* h1a = (const float*)&bh1;
  const float* h2a = (const float*)&bh2; const float* h3a = (const float*)&bh3;

  float4 hn, cn;
  float* hna = (float*)&hn; float* cna = (float*)&cn;
#pragma unroll
  for (int j = 0; j < 4; ++j) {
    float iv = sigm(zia[j] + b0a[j] + h0a[j]);
    float fv = sigm(zfa[j] + b1a[j] + h1a[j]);
    float gv = tanhx(zga[j] + b2a[j] + h2a[j]);
    float ov = sigm(zoa[j] + b3a[j] + h3a[j]);
    float c = fv * cva[j] + iv * gv;
    cna[j] = c;
    hna[j] = ov * tanhx(c);
  }
  size_t o = (size_t)b * 1024 + hc;
  *(float4*)(out + o) = hn;
  *(float4*)(out + 4194304 + o) = cn;
}

// ---------------------------------------------------------------------------
extern "C" void kernel_launch(void* const* d_in, const int* in_sizes, int n_in,
                              void* d_out, int out_size, void* d_ws, size_t ws_size,
                              hipStream_t stream) {
  const float* x  = (const float*)d_in[0];
  const float* ht = (const float*)d_in[1];
  const float* ct = (const float*)d_in[2];
  const float* wi = (const float*)d_in[3];
  const float* wh = (const float*)d_in[4];
  const float* bi = (const float*)d_in[5];
  const float* bh = (const float*)d_in[6];
  float* out = (float*)d_out;

  char* ws = (char*)d_ws;
  unsigned short* Abf = (unsigned short*)ws;                      // 16 MiB
  unsigned short* Wbf = (unsigned short*)(ws + (16u << 20));      // 16 MiB
  float* ifgo        = (float*)(ws + (32u << 20));                // 64 MiB

  pack_a<<<4096, 256, 0, stream>>>(x, ht, Abf);
  pack_w<<<2048, 256, 0, stream>>>(wi, wh, Wbf);
  gemm_bt<<<dim3(32, 32), 256, 0, stream>>>(Abf, Wbf, ifgo);
  lstm_ew<<<4096, 256, 0, stream>>>(ifgo, ct, bi, bh, out);
}

// Round 2
// 228.024 us; speedup vs baseline: 1.0272x; 1.0272x over previous
//
#include <hip/hip_runtime.h>
#include <stdint.h>

typedef __attribute__((ext_vector_type(8))) short short8;
typedef __attribute__((ext_vector_type(4))) float floatx4;

__device__ inline unsigned short f2bf(float x) {
  union { float f; unsigned int u; } v; v.f = x;
  unsigned int r = v.u + 0x7FFFu + ((v.u >> 16) & 1u);  // RNE
  return (unsigned short)(r >> 16);
}

// ---------------------------------------------------------------------------
// pack_a: A_bf16[4096][2048] = bf16([x | h]) ; 8 elems/thread, 16B stores
// ---------------------------------------------------------------------------
__global__ void pack_a(const float* __restrict__ x, const float* __restrict__ h,
                       unsigned short* __restrict__ A) {
  int idx = blockIdx.x * 256 + threadIdx.x;  // 1,048,576 threads
  int row = idx >> 8;                        // 0..4095
  int kc  = (idx & 255) << 3;                // 0..2040, step 8
  const float* src = (kc < 1024) ? (x + (size_t)row * 1024 + kc)
                                 : (h + (size_t)row * 1024 + (kc - 1024));
  float4 a = ((const float4*)src)[0];
  float4 b = ((const float4*)src)[1];
  uint4 o;
  o.x = f2bf(a.x) | ((unsigned)f2bf(a.y) << 16);
  o.y = f2bf(a.z) | ((unsigned)f2bf(a.w) << 16);
  o.z = f2bf(b.x) | ((unsigned)f2bf(b.y) << 16);
  o.w = f2bf(b.z) | ((unsigned)f2bf(b.w) << 16);
  *(uint4*)(A + (size_t)row * 2048 + kc) = o;
}

// ---------------------------------------------------------------------------
// pack_w: Wt_bf16[4096 n][2048 k] = bf16(transpose([w_i ; w_h]))
// n = gate*1024 + h (plain transpose); the GEMM's B staging permutes rows.
// grid: 2048 blocks = 64 n-tiles x 32 k-tiles, 256 threads
// ---------------------------------------------------------------------------
__global__ void pack_w(const float* __restrict__ wi, const float* __restrict__ wh,
                       unsigned short* __restrict__ Wt) {
  __shared__ float tile[64][65];
  int kt = blockIdx.x & 31;
  int nt = blockIdx.x >> 5;
  int k0 = kt << 6, n0 = nt << 6;
  const float* src = (k0 < 1024) ? (wi + (size_t)k0 * 4096)
                                 : (wh + (size_t)(k0 - 1024) * 4096);
  int t = threadIdx.x;
  int c4 = (t & 15) << 2, rr = t >> 4;
#pragma unroll
  for (int p = 0; p < 4; ++p) {
    int kk = rr + p * 16;
    float4 v = *(const float4*)(src + (size_t)kk * 4096 + n0 + c4);
    tile[kk][c4 + 0] = v.x; tile[kk][c4 + 1] = v.y;
    tile[kk][c4 + 2] = v.z; tile[kk][c4 + 3] = v.w;
  }
  __syncthreads();
  int k8 = (t & 7) << 3, nn = t >> 3;
#pragma unroll
  for (int p = 0; p < 2; ++p) {
    int n = nn + p * 32;
    uint4 o;
    o.x = f2bf(tile[k8 + 0][n]) | ((unsigned)f2bf(tile[k8 + 1][n]) << 16);
    o.y = f2bf(tile[k8 + 2][n]) | ((unsigned)f2bf(tile[k8 + 3][n]) << 16);
    o.z = f2bf(tile[k8 + 4][n]) | ((unsigned)f2bf(tile[k8 + 5][n]) << 16);
    o.w = f2bf(tile[k8 + 6][n]) | ((unsigned)f2bf(tile[k8 + 7][n]) << 16);
    *(uint4*)(Wt + (size_t)(n0 + n) * 2048 + k0 + k8) = o;
  }
}

// ---------------------------------------------------------------------------
// gemm_lstm: fused GEMM + LSTM gate epilogue.
// C-tile 128x128 where local col c = wn*64 + j*16 + ec maps to
//   gate = j = (c>>4)&3,  h = h0 + wn*16 + ec  (h0 = blockIdx.x*32)
// B staging loads Bt global row n(c) = gate*1024 + h.
// Epilogue: each lane's 4 j-fragments are the 4 gates of the same (row,h) —
// bias + sigmoid/tanh + cell update fully lane-local; writes h_new, c_new.
// ---------------------------------------------------------------------------
__device__ inline void gl_lds16(const void* g, void* l) {
  __builtin_amdgcn_global_load_lds(
      (const __attribute__((address_space(1))) void*)g,
      (__attribute__((address_space(3))) void*)l, 16, 0, 0);
}

__device__ inline float sigm(float x)  { return 1.0f / (1.0f + __expf(-x)); }
__device__ inline float tanhx(float x) { return 2.0f / (1.0f + __expf(-2.0f * x)) - 1.0f; }

__global__ void gemm_lstm(const unsigned short* __restrict__ A,
                          const unsigned short* __restrict__ Bt,
                          const float* __restrict__ ct,
                          const float* __restrict__ bi,
                          const float* __restrict__ bh,
                          float* __restrict__ out) {
  constexpr int K = 2048;
  __shared__ char AsB[128 * 64];  // 128 rows x 32 bf16 (64 B)
  __shared__ char BsB[128 * 64];
  const int tid  = threadIdx.x;
  const int lane = tid & 63;
  const int wave = tid >> 6;
  const int wm = wave >> 1, wn = wave & 1;
  const int m0 = blockIdx.y << 7;
  const int h0 = blockIdx.x << 5;  // 32 h per block

  // staging: thread covers 16B at flat offset tid*16 and +4096 in each tile
  const int r  = tid >> 2;          // local row 0..63 (and +64)
  const int cb = (tid & 3) << 4;    // byte col in 64B row
  const char* aS0 = (const char*)A + (size_t)(m0 + r) * K * 2 + cb;
  const char* aS1 = aS0 + (size_t)64 * K * 2;
  // B local col -> global Bt row: n(c) = ((c>>4)&3)*1024 + h0 + ((c>>6)<<4) + (c&15)
  const int nB0 = ((r >> 4) & 3) * 1024 + h0 + (r & 15);          // c = r   (<64)
  const int nB1 = ((r >> 4) & 3) * 1024 + h0 + 16 + (r & 15);     // c = r+64
  const char* bS0 = (const char*)Bt + (size_t)nB0 * K * 2 + cb;
  const char* bS1 = (const char*)Bt + (size_t)nB1 * K * 2 + cb;
  char* aD0 = AsB + tid * 16;
  char* aD1 = AsB + 4096 + tid * 16;
  char* bD0 = BsB + tid * 16;
  char* bD1 = BsB + 4096 + tid * 16;

  floatx4 acc[4][4] = {};
  const int rA = (wm << 6) + (lane & 15);   // LDS row for A frags (+f*16)
  const int rB = (wn << 6) + (lane & 15);   // LDS row for B frags (+f*16)
  const int kb = (lane >> 4) << 4;          // byte offset of k-quad (8 bf16)

  for (int ks = 0; ks < K; ks += 32) {
    gl_lds16(aS0, aD0); gl_lds16(aS1, aD1);
    gl_lds16(bS0, bD0); gl_lds16(bS1, bD1);
    aS0 += 64; aS1 += 64; bS0 += 64; bS1 += 64;
    __syncthreads();
    short8 af[4], bfr[4];
#pragma unroll
    for (int f = 0; f < 4; ++f) {
      af[f]  = *(const short8*)(AsB + (rA + f * 16) * 64 + kb);
      bfr[f] = *(const short8*)(BsB + (rB + f * 16) * 64 + kb);
    }
#pragma unroll
    for (int i = 0; i < 4; ++i)
#pragma unroll
      for (int j = 0; j < 4; ++j)
        acc[i][j] = __builtin_amdgcn_mfma_f32_16x16x32_bf16(af[i], bfr[j], acc[i][j], 0, 0, 0);
    __syncthreads();
  }

  // ---- fused LSTM epilogue ----
  // C/D map: col=lane&15, row=(lane>>4)*4+reg. Lane's j-fragment = gate j.
  const int er = (lane >> 4) << 2;
  const int ec = lane & 15;
  const int h  = h0 + (wn << 4) + ec;
  float bias[4];
#pragma unroll
  for (int j = 0; j < 4; ++j) bias[j] = bi[j * 1024 + h] + bh[j * 1024 + h];

#pragma unroll
  for (int i = 0; i < 4; ++i) {
#pragma unroll
    for (int rg = 0; rg < 4; ++rg) {
      int row = m0 + (wm << 6) + i * 16 + er + rg;
      size_t o = (size_t)row * 1024 + h;
      float cv = ct[o];
      float iv = sigm(acc[i][0][rg] + bias[0]);
      float fv = sigm(acc[i][1][rg] + bias[1]);
      float gv = tanhx(acc[i][2][rg] + bias[2]);
      float ov = sigm(acc[i][3][rg] + bias[3]);
      float cn = fv * cv + iv * gv;
      out[o] = ov * tanhx(cn);
      out[4194304 + o] = cn;
    }
  }
}

// ---------------------------------------------------------------------------
extern "C" void kernel_launch(void* const* d_in, const int* in_sizes, int n_in,
                              void* d_out, int out_size, void* d_ws, size_t ws_size,
                              hipStream_t stream) {
  const float* x  = (const float*)d_in[0];
  const float* ht = (const float*)d_in[1];
  const float* ct = (const float*)d_in[2];
  const float* wi = (const float*)d_in[3];
  const float* wh = (const float*)d_in[4];
  const float* bi = (const float*)d_in[5];
  const float* bh = (const float*)d_in[6];
  float* out = (float*)d_out;

  char* ws = (char*)d_ws;
  unsigned short* Abf = (unsigned short*)ws;                 // 16 MiB
  unsigned short* Wbf = (unsigned short*)(ws + (16u << 20)); // 16 MiB

  pack_a<<<4096, 256, 0, stream>>>(x, ht, Abf);
  pack_w<<<2048, 256, 0, stream>>>(wi, wh, Wbf);
  gemm_lstm<<<dim3(32, 32), 256, 0, stream>>>(Abf, Wbf, ct, bi, bh, out);
}

// Round 3
// 225.169 us; speedup vs baseline: 1.0402x; 1.0127x over previous
//
#include <hip/hip_runtime.h>
#include <stdint.h>

typedef __attribute__((ext_vector_type(8))) short short8;
typedef __attribute__((ext_vector_type(4))) float floatx4;

__device__ inline unsigned short f2bf(float x) {
  union { float f; unsigned int u; } v; v.f = x;
  unsigned int r = v.u + 0x7FFFu + ((v.u >> 16) & 1u);  // RNE
  return (unsigned short)(r >> 16);
}

// ---------------------------------------------------------------------------
// pack_all: one dispatch does both packs.
//   blocks [0,4096):    A_bf16[4096][2048] = bf16([x | h])
//   blocks [4096,6144): Wt_perm[4096][2048] = bf16(W^T) with gate-interleaved
//                       row index R = (h>>5)*128 + ((h>>4)&1)*64 + g*16 + (h&15)
//                       so the GEMM's B staging reads LINEAR rows (L2-friendly)
//                       while the epilogue still gets j == gate.
// ---------------------------------------------------------------------------
__global__ void pack_all(const float* __restrict__ x, const float* __restrict__ h,
                         const float* __restrict__ wi, const float* __restrict__ wh,
                         unsigned short* __restrict__ A,
                         unsigned short* __restrict__ Wt) {
  int bid = blockIdx.x;
  int t = threadIdx.x;
  if (bid < 4096) {
    // ---- pack A ----
    int idx = bid * 256 + t;
    int row = idx >> 8;
    int kc  = (idx & 255) << 3;
    const float* src = (kc < 1024) ? (x + (size_t)row * 1024 + kc)
                                   : (h + (size_t)row * 1024 + (kc - 1024));
    float4 a = ((const float4*)src)[0];
    float4 b = ((const float4*)src)[1];
    uint4 o;
    o.x = f2bf(a.x) | ((unsigned)f2bf(a.y) << 16);
    o.y = f2bf(a.z) | ((unsigned)f2bf(a.w) << 16);
    o.z = f2bf(b.x) | ((unsigned)f2bf(b.y) << 16);
    o.w = f2bf(b.z) | ((unsigned)f2bf(b.w) << 16);
    *(uint4*)(A + (size_t)row * 2048 + kc) = o;
  } else {
    // ---- pack W^T (permuted rows) ----
    __shared__ float tile[64][65];
    int b2 = bid - 4096;
    int kt = b2 & 31;
    int nt = b2 >> 5;
    int k0 = kt << 6, n0 = nt << 6;
    const float* src = (k0 < 1024) ? (wi + (size_t)k0 * 4096)
                                   : (wh + (size_t)(k0 - 1024) * 4096);
    int c4 = (t & 15) << 2, rr = t >> 4;
#pragma unroll
    for (int p = 0; p < 4; ++p) {
      int kk = rr + p * 16;
      float4 v = *(const float4*)(src + (size_t)kk * 4096 + n0 + c4);
      tile[kk][c4 + 0] = v.x; tile[kk][c4 + 1] = v.y;
      tile[kk][c4 + 2] = v.z; tile[kk][c4 + 3] = v.w;
    }
    __syncthreads();
    int k8 = (t & 7) << 3, nn = t >> 3;
#pragma unroll
    for (int p = 0; p < 2; ++p) {
      int n = n0 + nn + p * 32;          // global N index (gate*1024 + h)
      int hh = n & 1023, g = n >> 10;
      int R = ((hh >> 5) << 7) + (((hh >> 4) & 1) << 6) + (g << 4) + (hh & 15);
      int nl = nn + p * 32;
      uint4 o;
      o.x = f2bf(tile[k8 + 0][nl]) | ((unsigned)f2bf(tile[k8 + 1][nl]) << 16);
      o.y = f2bf(tile[k8 + 2][nl]) | ((unsigned)f2bf(tile[k8 + 3][nl]) << 16);
      o.z = f2bf(tile[k8 + 4][nl]) | ((unsigned)f2bf(tile[k8 + 5][nl]) << 16);
      o.w = f2bf(tile[k8 + 6][nl]) | ((unsigned)f2bf(tile[k8 + 7][nl]) << 16);
      *(uint4*)(Wt + (size_t)R * 2048 + k0 + k8) = o;
    }
  }
}

// ---------------------------------------------------------------------------
// gemm_lstm: fused GEMM + LSTM epilogue, round-1 LINEAR staging on both A and
// the permuted W buffer. ct/bias preloaded before the K-loop to hide miss
// latency under compute.
// ---------------------------------------------------------------------------
__device__ inline void gl_lds16(const void* g, void* l) {
  __builtin_amdgcn_global_load_lds(
      (const __attribute__((address_space(1))) void*)g,
      (__attribute__((address_space(3))) void*)l, 16, 0, 0);
}

__device__ inline float sigm(float x)  { return 1.0f / (1.0f + __expf(-x)); }
__device__ inline float tanhx(float x) { return 2.0f / (1.0f + __expf(-2.0f * x)) - 1.0f; }

__global__ void gemm_lstm(const unsigned short* __restrict__ A,
                          const unsigned short* __restrict__ Bt,
                          const float* __restrict__ ct,
                          const float* __restrict__ bi,
                          const float* __restrict__ bh,
                          float* __restrict__ out) {
  constexpr int K = 2048;
  __shared__ char AsB[128 * 64];  // 128 rows x 32 bf16 (64 B)
  __shared__ char BsB[128 * 64];
  const int tid  = threadIdx.x;
  const int lane = tid & 63;
  const int wave = tid >> 6;
  const int wm = wave >> 1, wn = wave & 1;
  const int m0 = blockIdx.y << 7;
  const int n0 = blockIdx.x << 7;   // linear row block in permuted W
  const int h0 = blockIdx.x << 5;   // 32 h per block

  // ---- early preload of epilogue operands (latency hidden by K-loop) ----
  const int er = (lane >> 4) << 2;
  const int ec = lane & 15;
  const int h  = h0 + (wn << 4) + ec;
  float bias[4];
#pragma unroll
  for (int j = 0; j < 4; ++j) bias[j] = bi[j * 1024 + h] + bh[j * 1024 + h];
  float cpre[4][4];
#pragma unroll
  for (int i = 0; i < 4; ++i)
#pragma unroll
    for (int rg = 0; rg < 4; ++rg) {
      int row = m0 + (wm << 6) + i * 16 + er + rg;
      cpre[i][rg] = ct[(size_t)row * 1024 + h];
    }

  // ---- staging addresses (linear rows, round-1 structure) ----
  const int r  = tid >> 2;
  const int cb = (tid & 3) << 4;
  const char* aS0 = (const char*)A + (size_t)(m0 + r) * K * 2 + cb;
  const char* aS1 = aS0 + (size_t)64 * K * 2;
  const char* bS0 = (const char*)Bt + (size_t)(n0 + r) * K * 2 + cb;
  const char* bS1 = bS0 + (size_t)64 * K * 2;
  char* aD0 = AsB + tid * 16;
  char* aD1 = AsB + 4096 + tid * 16;
  char* bD0 = BsB + tid * 16;
  char* bD1 = BsB + 4096 + tid * 16;

  floatx4 acc[4][4] = {};
  const int rA = (wm << 6) + (lane & 15);
  const int rB = (wn << 6) + (lane & 15);
  const int kb = (lane >> 4) << 4;

  for (int ks = 0; ks < K; ks += 32) {
    gl_lds16(aS0, aD0); gl_lds16(aS1, aD1);
    gl_lds16(bS0, bD0); gl_lds16(bS1, bD1);
    aS0 += 64; aS1 += 64; bS0 += 64; bS1 += 64;
    __syncthreads();
    short8 af[4], bfr[4];
#pragma unroll
    for (int f = 0; f < 4; ++f) {
      af[f]  = *(const short8*)(AsB + (rA + f * 16) * 64 + kb);
      bfr[f] = *(const short8*)(BsB + (rB + f * 16) * 64 + kb);
    }
#pragma unroll
    for (int i = 0; i < 4; ++i)
#pragma unroll
      for (int j = 0; j < 4; ++j)
        acc[i][j] = __builtin_amdgcn_mfma_f32_16x16x32_bf16(af[i], bfr[j], acc[i][j], 0, 0, 0);
    __syncthreads();
  }

  // ---- fused LSTM epilogue: lane-local, j == gate ----
#pragma unroll
  for (int i = 0; i < 4; ++i) {
#pragma unroll
    for (int rg = 0; rg < 4; ++rg) {
      int row = m0 + (wm << 6) + i * 16 + er + rg;
      size_t o = (size_t)row * 1024 + h;
      float iv = sigm(acc[i][0][rg] + bias[0]);
      float fv = sigm(acc[i][1][rg] + bias[1]);
      float gv = tanhx(acc[i][2][rg] + bias[2]);
      float ov = sigm(acc[i][3][rg] + bias[3]);
      float cn = fv * cpre[i][rg] + iv * gv;
      out[o] = ov * tanhx(cn);
      out[4194304 + o] = cn;
    }
  }
}

// ---------------------------------------------------------------------------
extern "C" void kernel_launch(void* const* d_in, const int* in_sizes, int n_in,
                              void* d_out, int out_size, void* d_ws, size_t ws_size,
                              hipStream_t stream) {
  const float* x  = (const float*)d_in[0];
  const float* ht = (const float*)d_in[1];
  const float* ct = (const float*)d_in[2];
  const float* wi = (const float*)d_in[3];
  const float* wh = (const float*)d_in[4];
  const float* bi = (const float*)d_in[5];
  const float* bh = (const float*)d_in[6];
  float* out = (float*)d_out;

  char* ws = (char*)d_ws;
  unsigned short* Abf = (unsigned short*)ws;                 // 16 MiB
  unsigned short* Wbf = (unsigned short*)(ws + (16u << 20)); // 16 MiB

  pack_all<<<6144, 256, 0, stream>>>(x, ht, wi, wh, Abf, Wbf);
  gemm_lstm<<<dim3(32, 32), 256, 0, stream>>>(Abf, Wbf, ct, bi, bh, out);
}

// Round 4
// 204.930 us; speedup vs baseline: 1.1430x; 1.0988x over previous
//
#include <hip/hip_runtime.h>
#include <stdint.h>

typedef __attribute__((ext_vector_type(8))) short short8;
typedef __attribute__((ext_vector_type(4))) float floatx4;

__device__ inline unsigned short f2bf(float x) {
  union { float f; unsigned int u; } v; v.f = x;
  unsigned int r = v.u + 0x7FFFu + ((v.u >> 16) & 1u);  // RNE
  return (unsigned short)(r >> 16);
}

// ---------------------------------------------------------------------------
// pack_all: one dispatch does both packs.
//   blocks [0,4096):    A_bf16[4096][2048] = bf16([x | h])
//   blocks [4096,6144): Wt_perm[4096][2048] = bf16(W^T) with gate-interleaved
//                       row index R = (h>>5)*128 + ((h>>4)&1)*64 + g*16 + (h&15)
//                       so the GEMM's B staging reads LINEAR rows while the
//                       epilogue gets j == gate.
// ---------------------------------------------------------------------------
__global__ void pack_all(const float* __restrict__ x, const float* __restrict__ h,
                         const float* __restrict__ wi, const float* __restrict__ wh,
                         unsigned short* __restrict__ A,
                         unsigned short* __restrict__ Wt) {
  int bid = blockIdx.x;
  int t = threadIdx.x;
  if (bid < 4096) {
    int idx = bid * 256 + t;
    int row = idx >> 8;
    int kc  = (idx & 255) << 3;
    const float* src = (kc < 1024) ? (x + (size_t)row * 1024 + kc)
                                   : (h + (size_t)row * 1024 + (kc - 1024));
    float4 a = ((const float4*)src)[0];
    float4 b = ((const float4*)src)[1];
    uint4 o;
    o.x = f2bf(a.x) | ((unsigned)f2bf(a.y) << 16);
    o.y = f2bf(a.z) | ((unsigned)f2bf(a.w) << 16);
    o.z = f2bf(b.x) | ((unsigned)f2bf(b.y) << 16);
    o.w = f2bf(b.z) | ((unsigned)f2bf(b.w) << 16);
    *(uint4*)(A + (size_t)row * 2048 + kc) = o;
  } else {
    __shared__ float tile[64][65];
    int b2 = bid - 4096;
    int kt = b2 & 31;
    int nt = b2 >> 5;
    int k0 = kt << 6, n0 = nt << 6;
    const float* src = (k0 < 1024) ? (wi + (size_t)k0 * 4096)
                                   : (wh + (size_t)(k0 - 1024) * 4096);
    int c4 = (t & 15) << 2, rr = t >> 4;
#pragma unroll
    for (int p = 0; p < 4; ++p) {
      int kk = rr + p * 16;
      float4 v = *(const float4*)(src + (size_t)kk * 4096 + n0 + c4);
      tile[kk][c4 + 0] = v.x; tile[kk][c4 + 1] = v.y;
      tile[kk][c4 + 2] = v.z; tile[kk][c4 + 3] = v.w;
    }
    __syncthreads();
    int k8 = (t & 7) << 3, nn = t >> 3;
#pragma unroll
    for (int p = 0; p < 2; ++p) {
      int n = n0 + nn + p * 32;          // global N index (gate*1024 + h)
      int hh = n & 1023, g = n >> 10;
      int R = ((hh >> 5) << 7) + (((hh >> 4) & 1) << 6) + (g << 4) + (hh & 15);
      int nl = nn + p * 32;
      uint4 o;
      o.x = f2bf(tile[k8 + 0][nl]) | ((unsigned)f2bf(tile[k8 + 1][nl]) << 16);
      o.y = f2bf(tile[k8 + 2][nl]) | ((unsigned)f2bf(tile[k8 + 3][nl]) << 16);
      o.z = f2bf(tile[k8 + 4][nl]) | ((unsigned)f2bf(tile[k8 + 5][nl]) << 16);
      o.w = f2bf(tile[k8 + 6][nl]) | ((unsigned)f2bf(tile[k8 + 7][nl]) << 16);
      *(uint4*)(Wt + (size_t)R * 2048 + k0 + k8) = o;
    }
  }
}

// ---------------------------------------------------------------------------
// gemm_lstm: fused GEMM + LSTM epilogue.
// BK=64 (128 B LDS rows, 32 iters, 32 MFMA per barrier pair) with XOR-8
// chunk swizzle: LDS row r holds global chunk c at physical slot c ^ (r&7),
// achieved by permuting the STAGING SOURCE (gl_lds16 dest must stay
// base + lane*16). Fragment reads then hit 2 lanes/bank (free per m136).
// ---------------------------------------------------------------------------
__device__ inline void gl_lds16(const void* g, void* l) {
  __builtin_amdgcn_global_load_lds(
      (const __attribute__((address_space(1))) void*)g,
      (__attribute__((address_space(3))) void*)l, 16, 0, 0);
}

__device__ inline float sigm(float x)  { return 1.0f / (1.0f + __expf(-x)); }
__device__ inline float tanhx(float x) { return 2.0f / (1.0f + __expf(-2.0f * x)) - 1.0f; }

__global__ void __launch_bounds__(256) gemm_lstm(
    const unsigned short* __restrict__ A,
    const unsigned short* __restrict__ Bt,
    const float* __restrict__ ct,
    const float* __restrict__ bi,
    const float* __restrict__ bh,
    float* __restrict__ out) {
  constexpr int K = 2048;
  __shared__ char AsB[128 * 128];  // 128 rows x 64 bf16 (128 B)
  __shared__ char BsB[128 * 128];
  const int tid  = threadIdx.x;
  const int lane = tid & 63;
  const int wave = tid >> 6;
  const int wm = wave >> 1, wn = wave & 1;
  const int m0 = blockIdx.y << 7;
  const int n0 = blockIdx.x << 7;   // linear row block in permuted W
  const int h0 = blockIdx.x << 5;   // 32 h per block

  // bias preload (tiny, latency hidden by K-loop)
  const int er = (lane >> 4) << 2;
  const int ec = lane & 15;
  const int h  = h0 + (wn << 4) + ec;
  float bias[4];
#pragma unroll
  for (int j = 0; j < 4; ++j) bias[j] = bi[j * 1024 + h] + bh[j * 1024 + h];

  // ---- staging: 4 passes/matrix; pass p covers LDS rows p*32 + (tid>>3),
  // physical chunk tid&7; source chunk (tid&7) ^ (row&7) ----
  const int sr = tid >> 3;                              // 0..31
  const int cs = ((tid & 7) ^ (sr & 7)) << 4;           // source chunk bytes
  const char* aS[4];
  const char* bS[4];
#pragma unroll
  for (int p = 0; p < 4; ++p) {
    aS[p] = (const char*)A  + (size_t)(m0 + p * 32 + sr) * K * 2 + cs;
    bS[p] = (const char*)Bt + (size_t)(n0 + p * 32 + sr) * K * 2 + cs;
  }
  char* aD = AsB + tid * 16;
  char* bD = BsB + tid * 16;

  floatx4 acc[4][4] = {};
  const int rA = (wm << 6) + (lane & 15);
  const int rB = (wn << 6) + (lane & 15);
  const int keyc = lane & 7;
  const int kq   = lane >> 4;
  const int c0 = ((kq ^ keyc) << 4);          // kk=0 physical chunk bytes
  const int c1 = (((4 + kq) ^ keyc) << 4);    // kk=1

  for (int ks = 0; ks < K; ks += 64) {
#pragma unroll
    for (int p = 0; p < 4; ++p) { gl_lds16(aS[p], aD + p * 4096); aS[p] += 128; }
#pragma unroll
    for (int p = 0; p < 4; ++p) { gl_lds16(bS[p], bD + p * 4096); bS[p] += 128; }
    __syncthreads();
    {
      short8 af[4], bfr[4];
#pragma unroll
      for (int f = 0; f < 4; ++f) {
        af[f]  = *(const short8*)(AsB + (rA + f * 16) * 128 + c0);
        bfr[f] = *(const short8*)(BsB + (rB + f * 16) * 128 + c0);
      }
#pragma unroll
      for (int i = 0; i < 4; ++i)
#pragma unroll
        for (int j = 0; j < 4; ++j)
          acc[i][j] = __builtin_amdgcn_mfma_f32_16x16x32_bf16(af[i], bfr[j], acc[i][j], 0, 0, 0);
    }
    {
      short8 af[4], bfr[4];
#pragma unroll
      for (int f = 0; f < 4; ++f) {
        af[f]  = *(const short8*)(AsB + (rA + f * 16) * 128 + c1);
        bfr[f] = *(const short8*)(BsB + (rB + f * 16) * 128 + c1);
      }
#pragma unroll
      for (int i = 0; i < 4; ++i)
#pragma unroll
        for (int j = 0; j < 4; ++j)
          acc[i][j] = __builtin_amdgcn_mfma_f32_16x16x32_bf16(af[i], bfr[j], acc[i][j], 0, 0, 0);
    }
    __syncthreads();
  }

  // ---- fused LSTM epilogue: batch ct loads first (one overlapped miss),
  // then lane-local gates (j == gate) ----
  float cv[4][4];
#pragma unroll
  for (int i = 0; i < 4; ++i)
#pragma unroll
    for (int rg = 0; rg < 4; ++rg) {
      int row = m0 + (wm << 6) + i * 16 + er + rg;
      cv[i][rg] = ct[(size_t)row * 1024 + h];
    }
#pragma unroll
  for (int i = 0; i < 4; ++i) {
#pragma unroll
    for (int rg = 0; rg < 4; ++rg) {
      int row = m0 + (wm << 6) + i * 16 + er + rg;
      size_t o = (size_t)row * 1024 + h;
      float iv = sigm(acc[i][0][rg] + bias[0]);
      float fv = sigm(acc[i][1][rg] + bias[1]);
      float gv = tanhx(acc[i][2][rg] + bias[2]);
      float ov = sigm(acc[i][3][rg] + bias[3]);
      float cn = fv * cv[i][rg] + iv * gv;
      out[o] = ov * tanhx(cn);
      out[4194304 + o] = cn;
    }
  }
}

// ---------------------------------------------------------------------------
extern "C" void kernel_launch(void* const* d_in, const int* in_sizes, int n_in,
                              void* d_out, int out_size, void* d_ws, size_t ws_size,
                              hipStream_t stream) {
  const float* x  = (const float*)d_in[0];
  const float* ht = (const float*)d_in[1];
  const float* ct = (const float*)d_in[2];
  const float* wi = (const float*)d_in[3];
  const float* wh = (const float*)d_in[4];
  const float* bi = (const float*)d_in[5];
  const float* bh = (const float*)d_in[6];
  float* out = (float*)d_out;

  char* ws = (char*)d_ws;
  unsigned short* Abf = (unsigned short*)ws;                 // 16 MiB
  unsigned short* Wbf = (unsigned short*)(ws + (16u << 20)); // 16 MiB

  pack_all<<<6144, 256, 0, stream>>>(x, ht, wi, wh, Abf, Wbf);
  gemm_lstm<<<dim3(32, 32), 256, 0, stream>>>(Abf, Wbf, ct, bi, bh, out);
}

// Round 5
// 197.749 us; speedup vs baseline: 1.1845x; 1.0363x over previous
//
#include <hip/hip_runtime.h>
#include <stdint.h>

typedef __attribute__((ext_vector_type(8))) short short8;
typedef __attribute__((ext_vector_type(4))) float floatx4;

__device__ inline unsigned short f2bf(float x) {
  union { float f; unsigned int u; } v; v.f = x;
  unsigned int r = v.u + 0x7FFFu + ((v.u >> 16) & 1u);  // RNE
  return (unsigned short)(r >> 16);
}

// ---------------------------------------------------------------------------
// pack_all: one dispatch does both packs.
//   blocks [0,4096):    A_bf16[4096][2048] = bf16([x | h])
//   blocks [4096,6144): Wt_perm[4096][2048] = bf16(W^T) with gate-interleaved
//                       row index R = (h>>5)*128 + ((h>>4)&1)*64 + g*16 + (h&15)
//                       so the GEMM's B staging reads LINEAR rows while the
//                       epilogue gets j == gate.
// ---------------------------------------------------------------------------
__global__ void pack_all(const float* __restrict__ x, const float* __restrict__ h,
                         const float* __restrict__ wi, const float* __restrict__ wh,
                         unsigned short* __restrict__ A,
                         unsigned short* __restrict__ Wt) {
  int bid = blockIdx.x;
  int t = threadIdx.x;
  if (bid < 4096) {
    int idx = bid * 256 + t;
    int row = idx >> 8;
    int kc  = (idx & 255) << 3;
    const float* src = (kc < 1024) ? (x + (size_t)row * 1024 + kc)
                                   : (h + (size_t)row * 1024 + (kc - 1024));
    float4 a = ((const float4*)src)[0];
    float4 b = ((const float4*)src)[1];
    uint4 o;
    o.x = f2bf(a.x) | ((unsigned)f2bf(a.y) << 16);
    o.y = f2bf(a.z) | ((unsigned)f2bf(a.w) << 16);
    o.z = f2bf(b.x) | ((unsigned)f2bf(b.y) << 16);
    o.w = f2bf(b.z) | ((unsigned)f2bf(b.w) << 16);
    *(uint4*)(A + (size_t)row * 2048 + kc) = o;
  } else {
    __shared__ float tile[64][65];
    int b2 = bid - 4096;
    int kt = b2 & 31;
    int nt = b2 >> 5;
    int k0 = kt << 6, n0 = nt << 6;
    const float* src = (k0 < 1024) ? (wi + (size_t)k0 * 4096)
                                   : (wh + (size_t)(k0 - 1024) * 4096);
    int c4 = (t & 15) << 2, rr = t >> 4;
#pragma unroll
    for (int p = 0; p < 4; ++p) {
      int kk = rr + p * 16;
      float4 v = *(const float4*)(src + (size_t)kk * 4096 + n0 + c4);
      tile[kk][c4 + 0] = v.x; tile[kk][c4 + 1] = v.y;
      tile[kk][c4 + 2] = v.z; tile[kk][c4 + 3] = v.w;
    }
    __syncthreads();
    int k8 = (t & 7) << 3, nn = t >> 3;
#pragma unroll
    for (int p = 0; p < 2; ++p) {
      int n = n0 + nn + p * 32;          // global N index (gate*1024 + h)
      int hh = n & 1023, g = n >> 10;
      int R = ((hh >> 5) << 7) + (((hh >> 4) & 1) << 6) + (g << 4) + (hh & 15);
      int nl = nn + p * 32;
      uint4 o;
      o.x = f2bf(tile[k8 + 0][nl]) | ((unsigned)f2bf(tile[k8 + 1][nl]) << 16);
      o.y = f2bf(tile[k8 + 2][nl]) | ((unsigned)f2bf(tile[k8 + 3][nl]) << 16);
      o.z = f2bf(tile[k8 + 4][nl]) | ((unsigned)f2bf(tile[k8 + 5][nl]) << 16);
      o.w = f2bf(tile[k8 + 6][nl]) | ((unsigned)f2bf(tile[k8 + 7][nl]) << 16);
      *(uint4*)(Wt + (size_t)R * 2048 + k0 + k8) = o;
    }
  }
}

// ---------------------------------------------------------------------------
// gemm_lstm: fused GEMM + LSTM epilogue.
// BK=64, XOR-8 source-chunk swizzle (conflict-free, verified R4: 0 conflicts).
// This round: staging addresses split into wave-uniform (SGPR) + one shared
// per-lane offset so the compiler emits saddr-form global_load_lds — kills
// 8 VGPR pointer pairs + 16 per-iter v_adds. LDS fragment bases hoisted
// (loop-invariant, f*2048 goes in the ds_read immediate offset).
// __launch_bounds__(256,3) pins unified regs <=170 -> 3 blocks/CU.
// ---------------------------------------------------------------------------
__device__ inline void gl_lds16(const void* g, void* l) {
  __builtin_amdgcn_global_load_lds(
      (const __attribute__((address_space(1))) void*)g,
      (__attribute__((address_space(3))) void*)l, 16, 0, 0);
}

__device__ inline float sigm(float x)  { return 1.0f / (1.0f + __expf(-x)); }
__device__ inline float tanhx(float x) { return 2.0f / (1.0f + __expf(-2.0f * x)) - 1.0f; }

__global__ void __launch_bounds__(256, 3) gemm_lstm(
    const unsigned short* __restrict__ A,
    const unsigned short* __restrict__ Bt,
    const float* __restrict__ ct,
    const float* __restrict__ bi,
    const float* __restrict__ bh,
    float* __restrict__ out) {
  constexpr int K = 2048;
  __shared__ char AsB[128 * 128];  // 128 rows x 64 bf16 (128 B)
  __shared__ char BsB[128 * 128];
  const int tid  = threadIdx.x;
  const int lane = tid & 63;
  const int wave = tid >> 6;
  const int wm = wave >> 1, wn = wave & 1;
  const int m0 = blockIdx.y << 7;
  const int n0 = blockIdx.x << 7;   // linear row block in permuted W
  const int h0 = blockIdx.x << 5;   // 32 h per block

  // epilogue lane mapping + bias preload (latency hidden by K-loop)
  const int er = (lane >> 4) << 2;
  const int ec = lane & 15;
  const int h  = h0 + (wn << 4) + ec;
  float bias[4];
#pragma unroll
  for (int j = 0; j < 4; ++j) bias[j] = bi[j * 1024 + h] + bh[j * 1024 + h];

  // ---- staging: uniform base (SGPR) + ONE shared per-lane byte offset ----
  const int sr = tid >> 3;                              // LDS row 0..31 (+p*32)
  const int cs = ((tid & 7) ^ (sr & 7)) << 4;           // XOR-swizzled source chunk
  const unsigned voff = (unsigned)sr * 4096u + (unsigned)cs;  // per-lane, invariant
  const char* aBase = (const char*)A  + (size_t)m0 * 4096;    // row = 4096 B
  const char* bBase = (const char*)Bt + (size_t)n0 * 4096;
  char* aD = AsB + tid * 16;
  char* bD = BsB + tid * 16;

  floatx4 acc[4][4] = {};
  // LDS fragment bases (loop-invariant; f*16 rows -> +f*2048 immediate)
  const int rA = (wm << 6) + (lane & 15);
  const int rB = (wn << 6) + (lane & 15);
  const int keyc = lane & 7;
  const int kq   = lane >> 4;
  const char* aF0 = AsB + rA * 128 + ((kq ^ keyc) << 4);
  const char* aF1 = AsB + rA * 128 + (((4 + kq) ^ keyc) << 4);
  const char* bF0 = BsB + rB * 128 + ((kq ^ keyc) << 4);
  const char* bF1 = BsB + rB * 128 + (((4 + kq) ^ keyc) << 4);

  for (int ks = 0; ks < K; ks += 64) {
    const char* aIt = aBase + ks * 2;   // uniform
    const char* bIt = bBase + ks * 2;   // uniform
#pragma unroll
    for (int p = 0; p < 4; ++p) gl_lds16(aIt + p * 131072 + voff, aD + p * 4096);
#pragma unroll
    for (int p = 0; p < 4; ++p) gl_lds16(bIt + p * 131072 + voff, bD + p * 4096);
    __syncthreads();
    {
      short8 af[4], bfr[4];
#pragma unroll
      for (int f = 0; f < 4; ++f) {
        af[f]  = *(const short8*)(aF0 + f * 2048);
        bfr[f] = *(const short8*)(bF0 + f * 2048);
      }
#pragma unroll
      for (int i = 0; i < 4; ++i)
#pragma unroll
        for (int j = 0; j < 4; ++j)
          acc[i][j] = __builtin_amdgcn_mfma_f32_16x16x32_bf16(af[i], bfr[j], acc[i][j], 0, 0, 0);
    }
    {
      short8 af[4], bfr[4];
#pragma unroll
      for (int f = 0; f < 4; ++f) {
        af[f]  = *(const short8*)(aF1 + f * 2048);
        bfr[f] = *(const short8*)(bF1 + f * 2048);
      }
#pragma unroll
      for (int i = 0; i < 4; ++i)
#pragma unroll
        for (int j = 0; j < 4; ++j)
          acc[i][j] = __builtin_amdgcn_mfma_f32_16x16x32_bf16(af[i], bfr[j], acc[i][j], 0, 0, 0);
    }
    __syncthreads();
  }

  // ---- fused LSTM epilogue: batch ct loads (one overlapped miss window),
  // then lane-local gates (j == gate) ----
  float cv[4][4];
#pragma unroll
  for (int i = 0; i < 4; ++i)
#pragma unroll
    for (int rg = 0; rg < 4; ++rg) {
      int row = m0 + (wm << 6) + i * 16 + er + rg;
      cv[i][rg] = ct[(size_t)row * 1024 + h];
    }
#pragma unroll
  for (int i = 0; i < 4; ++i) {
#pragma unroll
    for (int rg = 0; rg < 4; ++rg) {
      int row = m0 + (wm << 6) + i * 16 + er + rg;
      size_t o = (size_t)row * 1024 + h;
      float iv = sigm(acc[i][0][rg] + bias[0]);
      float fv = sigm(acc[i][1][rg] + bias[1]);
      float gv = tanhx(acc[i][2][rg] + bias[2]);
      float ov = sigm(acc[i][3][rg] + bias[3]);
      float cn = fv * cv[i][rg] + iv * gv;
      out[o] = ov * tanhx(cn);
      out[4194304 + o] = cn;
    }
  }
}

// ---------------------------------------------------------------------------
extern "C" void kernel_launch(void* const* d_in, const int* in_sizes, int n_in,
                              void* d_out, int out_size, void* d_ws, size_t ws_size,
                              hipStream_t stream) {
  const float* x  = (const float*)d_in[0];
  const float* ht = (const float*)d_in[1];
  const float* ct = (const float*)d_in[2];
  const float* wi = (const float*)d_in[3];
  const float* wh = (const float*)d_in[4];
  const float* bi = (const float*)d_in[5];
  const float* bh = (const float*)d_in[6];
  float* out = (float*)d_out;

  char* ws = (char*)d_ws;
  unsigned short* Abf = (unsigned short*)ws;                 // 16 MiB
  unsigned short* Wbf = (unsigned short*)(ws + (16u << 20)); // 16 MiB

  pack_all<<<6144, 256, 0, stream>>>(x, ht, wi, wh, Abf, Wbf);
  gemm_lstm<<<dim3(32, 32), 256, 0, stream>>>(Abf, Wbf, ct, bi, bh, out);
}